// Round 11
// baseline (50.280 us; speedup 1.0000x reference)
//
#include <hip/hip_runtime.h>

#define HH 128
#define WW 256
#define CV_C 32
#define DISP 200

typedef __attribute__((ext_vector_type(4))) float f32x4;
typedef __attribute__((ext_vector_type(8))) short bf16x8;

__device__ inline unsigned short f2bf(float f) {
  unsigned int u = __float_as_uint(f);
  u = (u + 0x7FFFu + ((u >> 16) & 1u)) >> 16;  // RNE
  return (unsigned short)u;
}

__device__ inline float bf2f(short s) {
  return __uint_as_float(((unsigned int)(unsigned short)s) << 16);
}

// XCD-consistent job mapping for 512-block kernels (4 x-tiles x 128 y):
// XCD k = bid&7 owns y in [k*16, k*16+16) across ALL kernels, so each row's
// producer and consumer (and y-halo neighbors) share one XCD's L2.
#define MAP_YX4()                                   \
  const int slot = bid >> 3;                        \
  const int y = ((bid & 7) << 4) + (slot & 15);     \
  const int x0 = (slot >> 4) << 6;

// ---------------------------------------------------------------------------
// K1: blocks 0..511 cost-volume MFMA (critical path first), 512..1105 packs.
// CV: cost[d,y,x] = sum_c L[c,y,x]*R[c,y,x+d-200] -> cost_t bf16 [128][256][224]
// ---------------------------------------------------------------------------
__global__ __launch_bounds__(256) void k1_cv_pack(
    const float* __restrict__ left, const float* __restrict__ right,
    const float* __restrict__ w1, const float* __restrict__ w2,
    const float* __restrict__ w3, unsigned short* __restrict__ pw1,
    unsigned short* __restrict__ pb2, unsigned short* __restrict__ pb3,
    unsigned short* __restrict__ cost_t) {
  __shared__ unsigned short r_sh[272][40];  // 21760 B
  __shared__ unsigned short l_hi[64][40];   // 5120 B
  __shared__ unsigned short l_lo[64][40];   // 5120 B
  __shared__ unsigned short c_sh[64][224];  // 28672 B
  const int bid = blockIdx.x;
  const int tid = threadIdx.x;

  if (bid >= 512) {  // ---- weight packing ----
    const int b = bid - 512;
    if (b < 504) {  // pw1[chunk 7][pos 9][kg 4][n 64][j 8]
      const int idx = b * 256 + tid;
      const int j = idx & 7;
      const int n = (idx >> 3) & 63;
      const int kg = (idx >> 9) & 3;
      const int cp = idx >> 11;
      const int pos = cp % 9;
      const int chunk = cp / 9;
      const int ci = chunk * 32 + kg * 8 + j;
      float v = 0.f;
      if (ci < 200) v = w1[(n * 200 + ci) * 9 + pos];
      pw1[idx] = f2bf(v);
    } else if (b < 576) {  // pb2[pos 9][kc 2][kg 4][n 32][j 8]
      const int idx = (b - 504) * 256 + tid;
      const int j = idx & 7;
      const int n = (idx >> 3) & 31;
      const int kg = (idx >> 8) & 3;
      const int kc = (idx >> 10) & 1;
      const int pos = idx >> 11;
      const int ci = kc * 32 + kg * 8 + j;
      pb2[idx] = f2bf(w2[(n * 64 + ci) * 9 + pos]);
    } else {  // pb3[pos 9][kg 4][n 16(8 real)][j 8]
      const int idx = (b - 576) * 256 + tid;
      const int j = idx & 7;
      const int n = (idx >> 3) & 15;
      const int kg = (idx >> 7) & 3;
      const int pos = idx >> 9;
      const int ci = kg * 8 + j;
      float v = 0.f;
      if (n < 8) v = w3[(n * 32 + ci) * 9 + pos];
      pb3[idx] = f2bf(v);
    }
    return;
  }

  // ---- cost volume ----
  MAP_YX4();
  const int lane = tid & 63;
  const int wv = tid >> 6;
  const int col = lane & 15;
  const int kg = lane >> 4;

  for (int c = wv; c < CV_C; c += 4) {
    const float v = left[(c * HH + y) * WW + x0 + lane];
    const unsigned short h = f2bf(v);
    l_hi[lane][c] = h;
    l_lo[lane][c] = f2bf(v - bf2f(h));
  }
  // R-stage: p >= pmin <=> xp >= 0. Zero-prefill rows [0,pmin) x cols [0,32)
  // (vec8; disjoint from the load region -> no race), then load only groups
  // that intersect the valid range (uniform branch; skips up to 3 of 5).
  const int pmin = 208 - x0;  // x0 in {0,64,128,192} -> pmin in {208,...,16}
  {
    bf16x8 z = {0, 0, 0, 0, 0, 0, 0, 0};
    for (int s = tid; s < pmin * 4; s += 256)
      *reinterpret_cast<bf16x8*>(&r_sh[s >> 2][(s & 3) * 8]) = z;
  }
  const int pq_start = pmin & ~63;
  for (int c = wv; c < CV_C; c += 4) {
    for (int pq = pq_start; pq < 320; pq += 64) {
      const int p = pq + lane;
      if (p < 272 && p >= pmin) {
        const int xp = x0 - 208 + p;
        r_sh[p][c] = f2bf(right[(c * HH + y) * WW + xp]);
      }
    }
  }
  // c_sh: scatter provably covers all d in [0,200) for every row; zero only
  // the pad region d in [200,224) (3 vec8 slots x 64 rows = 192).
  if (tid < 192) {
    bf16x8 z = {0, 0, 0, 0, 0, 0, 0, 0};
    *reinterpret_cast<bf16x8*>(&c_sh[tid / 3][200 + (tid % 3) * 8]) = z;
  }
  __syncthreads();

  const bf16x8 b_hi = *(const bf16x8*)&l_hi[16 * wv + col][kg * 8];
  const bf16x8 b_lo = *(const bf16x8*)&l_lo[16 * wv + col][kg * 8];

  for (int t = 0; t < 14; ++t) {
    const int pq = 16 * (wv - t) + 208;
    const bf16x8 a_r = *(const bf16x8*)&r_sh[pq + col][kg * 8];
    f32x4 acc = {0.f, 0.f, 0.f, 0.f};
    acc = __builtin_amdgcn_mfma_f32_16x16x32_bf16(a_r, b_hi, acc, 0, 0, 0);
    acc = __builtin_amdgcn_mfma_f32_16x16x32_bf16(a_r, b_lo, acc, 0, 0, 0);
#pragma unroll
    for (int r = 0; r < 4; ++r) {
      const int d = 200 - 16 * t + kg * 4 + r - col;
      if (d >= 0 && d < DISP) c_sh[16 * wv + col][d] = f2bf(acc[r]);
    }
  }
  __syncthreads();

#pragma unroll
  for (int k = 0; k < 7; ++k) {
    const int s = k * 256 + tid;
    const int x = s / 28;
    const int dv = s - x * 28;
    *reinterpret_cast<bf16x8*>(&cost_t[(y * WW + x0 + x) * 224 + dv * 8]) =
        *reinterpret_cast<const bf16x8*>(&c_sh[x][dv * 8]);
  }
}

// ---------------------------------------------------------------------------
// K2: conv1 implicit GEMM bf16 MFMA, register-blocked 4M x 2N per wave.
// (round-10 body, unchanged)
// ---------------------------------------------------------------------------
__global__ __launch_bounds__(256) void conv1_mfma_kernel(
    const unsigned short* __restrict__ cost_t,  // [128][256][224]
    const unsigned short* __restrict__ pw,      // [7][9][4][64][8]
    const float* __restrict__ bias, const float* __restrict__ gam,
    const float* __restrict__ bet, const float* __restrict__ mean,
    const float* __restrict__ var, unsigned short* __restrict__ out_t) {
  __shared__ unsigned short a_sh[4 * 66 * 40];     // 21120 B
  __shared__ unsigned short b_sh[9 * 4 * 64 * 8];  // 36864 B (one chunk of pw)
  const int bid = blockIdx.x;
  const int tid = threadIdx.x;
  // XCD-consistent: XCD k = bid&7 owns y-pairs p in [8k, 8k+8).
  const int slot = bid >> 3;                       // [0,32)
  const int p = ((bid & 7) << 3) + (slot & 7);     // y-pair [0,64)
  const int y0 = p << 1;
  const int x0 = (slot >> 3) << 6;                 // [0,4)*64
  const int lane = tid & 63;
  const int wv = tid >> 6;
  const int r = wv >> 1;          // output row within pair
  const int n0 = (wv & 1) * 32;   // co half
  const int col = lane & 15;
  const int kg = lane >> 4;

  // staging slots: 4 rows x 66 x 4 q = 1056 vec8 slots, 5 iters/thread
  long goff[5];
  int laddr[5];
  bool gvalid[5], lvalid[5];
#pragma unroll
  for (int it = 0; it < 5; ++it) {
    const int i = tid + it * 256;
    lvalid[it] = i < 1056;
    const int row = i / 264;
    const int rem = i % 264;
    const int xx = rem >> 2;
    const int q = rem & 3;
    const int gy = y0 + row - 1;
    const int gx = x0 - 1 + xx;
    gvalid[it] = lvalid[it] && gy >= 0 && gy < HH && gx >= 0 && gx < WW;
    goff[it] = gvalid[it] ? (long)(gy * WW + gx) * 224 + q * 8 : 0;
    laddr[it] = (row * 66 + xx) * 40 + q * 8;
  }

  f32x4 acc[4][2];
#pragma unroll
  for (int i = 0; i < 4; ++i)
#pragma unroll
    for (int jx = 0; jx < 2; ++jx) acc[i][jx] = 0.f;

  const bf16x8* pwv = (const bf16x8*)pw;  // 2304 vec8 slots per chunk
  bf16x8* bsl = (bf16x8*)b_sh;
  const bf16x8 zero = {0, 0, 0, 0, 0, 0, 0, 0};
  bf16x8 stgA[5], stgB[9];

  // prologue: stage chunk 0 (A + B)
#pragma unroll
  for (int it = 0; it < 5; ++it)
    stgA[it] = gvalid[it] ? *reinterpret_cast<const bf16x8*>(&cost_t[goff[it]])
                          : zero;
#pragma unroll
  for (int it = 0; it < 9; ++it) stgB[it] = pwv[tid + it * 256];
#pragma unroll
  for (int it = 0; it < 5; ++it)
    if (lvalid[it]) *reinterpret_cast<bf16x8*>(&a_sh[laddr[it]]) = stgA[it];
#pragma unroll
  for (int it = 0; it < 9; ++it) bsl[tid + it * 256] = stgB[it];
  __syncthreads();

  for (int chunk = 0; chunk < 7; ++chunk) {
    if (chunk < 6) {  // prefetch next chunk into regs (hidden by MFMAs)
#pragma unroll
      for (int it = 0; it < 5; ++it)
        stgA[it] = gvalid[it] ? *reinterpret_cast<const bf16x8*>(
                                    &cost_t[goff[it] + (chunk + 1) * 32])
                              : zero;
      const bf16x8* pwn = pwv + (chunk + 1) * 2304;
#pragma unroll
      for (int it = 0; it < 9; ++it) stgB[it] = pwn[tid + it * 256];
    }
    const bf16x8* av = (const bf16x8*)a_sh;
#pragma unroll
    for (int pos = 0; pos < 9; ++pos) {
      const int ky = pos / 3;
      const int kx = pos % 3;
      const bf16x8 b0v = bsl[(pos * 4 + kg) * 64 + n0 + col];
      const bf16x8 b1v = bsl[(pos * 4 + kg) * 64 + n0 + 16 + col];
      bf16x8 af[4];
#pragma unroll
      for (int mt = 0; mt < 4; ++mt)
        af[mt] = av[((r + ky) * 66 + mt * 16 + col + kx) * 5 + kg];
#pragma unroll
      for (int mt = 0; mt < 4; ++mt) {
        acc[mt][0] =
            __builtin_amdgcn_mfma_f32_16x16x32_bf16(af[mt], b0v, acc[mt][0], 0, 0, 0);
        acc[mt][1] =
            __builtin_amdgcn_mfma_f32_16x16x32_bf16(af[mt], b1v, acc[mt][1], 0, 0, 0);
      }
    }
    if (chunk < 6) {
      __syncthreads();  // all waves done reading a_sh/b_sh for this chunk
#pragma unroll
      for (int it = 0; it < 5; ++it)
        if (lvalid[it]) *reinterpret_cast<bf16x8*>(&a_sh[laddr[it]]) = stgA[it];
#pragma unroll
      for (int it = 0; it < 9; ++it) bsl[tid + it * 256] = stgB[it];
      __syncthreads();  // new chunk visible
    }
  }

  // epilogue: bias + BN + ReLU -> o1_t NHWC bf16 [128][256][64]
  const int y = y0 + r;
#pragma unroll
  for (int nf = 0; nf < 2; ++nf) {
    const int c = n0 + nf * 16 + col;
    const float inv = rsqrtf(var[c] + 1e-5f);
    const float sc = gam[c] * inv;
    const float sh = bet[c] - mean[c] * sc;
    const float bb = bias[c];
#pragma unroll
    for (int mt = 0; mt < 4; ++mt) {
#pragma unroll
      for (int rr = 0; rr < 4; ++rr) {
        const int m = mt * 16 + kg * 4 + rr;
        float vv = (acc[mt][nf][rr] + bb) * sc + sh;
        vv = fmaxf(vv, 0.f);
        out_t[((y * WW + x0 + m) << 6) + c] = f2bf(vv);
      }
    }
  }
}

// ---------------------------------------------------------------------------
// K3: conv2 64->32, NHWC bf16, XOR-swizzled A-tile; full pb2 staged in LDS.
// ---------------------------------------------------------------------------
__global__ __launch_bounds__(256) void conv2_mfma_kernel(
    const unsigned short* __restrict__ in_t,  // [128][256][64]
    const unsigned short* __restrict__ pb,    // [9][2][4][32][8]
    const float* __restrict__ bias, const float* __restrict__ gam,
    const float* __restrict__ bet, const float* __restrict__ mean,
    const float* __restrict__ var, unsigned short* __restrict__ out_t) {
  __shared__ unsigned short a_sh[3 * 66 * 64];  // 25344 B
  __shared__ unsigned short b_sh[18432];        // 36864 B (all of pb2)
  char* const ab = (char*)a_sh;
  const int bid = blockIdx.x;
  const int tid = threadIdx.x;
  MAP_YX4();
  const int lane = tid & 63;
  const int wv = tid >> 6;
  const int m0 = (wv >> 1) * 32;
  const int n0 = (wv & 1) * 16;
  const int col = lane & 15;
  const int kg = lane >> 4;

  f32x4 acc[2];
  acc[0] = 0.f;
  acc[1] = 0.f;

  {  // stage all weights (2304 vec8 = 9/thread)
    const bf16x8* pbv = (const bf16x8*)pb;
    bf16x8* bsl = (bf16x8*)b_sh;
#pragma unroll
    for (int it = 0; it < 9; ++it) bsl[tid + it * 256] = pbv[tid + it * 256];
  }
  for (int i = tid; i < 1584; i += 256) {  // 3*66*8
    const int r = i >> 3;
    const int q = i & 7;
    const int rowy = r / 66;
    const int xx = r % 66;
    const int gy = y + rowy - 1;
    const int gx = x0 - 1 + xx;
    bf16x8 v = {0, 0, 0, 0, 0, 0, 0, 0};
    if (gy >= 0 && gy < HH && gx >= 0 && gx < WW)
      v = *reinterpret_cast<const bf16x8*>(&in_t[((gy * WW + gx) << 6) + q * 8]);
    const int byte = ((r << 7) + (q << 4)) ^ ((r & 7) << 4);
    *reinterpret_cast<bf16x8*>(ab + byte) = v;
  }
  __syncthreads();

  const bf16x8* bsl = (const bf16x8*)b_sh;
#pragma unroll
  for (int pos = 0; pos < 9; ++pos) {
    const int ky = pos / 3;
    const int kx = pos % 3;
#pragma unroll
    for (int kc = 0; kc < 2; ++kc) {
      const bf16x8 bv = bsl[((pos * 2 + kc) * 4 + kg) * 32 + n0 + col];
#pragma unroll
      for (int mf = 0; mf < 2; ++mf) {
        const int r = ky * 66 + m0 + mf * 16 + col + kx;
        const int byte = ((r << 7) + (kc << 6) + (kg << 4)) ^ ((r & 7) << 4);
        const bf16x8 av = *reinterpret_cast<const bf16x8*>(ab + byte);
        acc[mf] = __builtin_amdgcn_mfma_f32_16x16x32_bf16(av, bv, acc[mf], 0, 0, 0);
      }
    }
  }

  const int c = n0 + col;
  const float inv = rsqrtf(var[c] + 1e-5f);
  const float sc = gam[c] * inv;
  const float sh = bet[c] - mean[c] * sc;
  const float bb = bias[c];
#pragma unroll
  for (int mf = 0; mf < 2; ++mf) {
#pragma unroll
    for (int rr = 0; rr < 4; ++rr) {
      const int m = m0 + mf * 16 + kg * 4 + rr;
      float vv = (acc[mf][rr] + bb) * sc + sh;
      vv = fmaxf(vv, 0.f);
      out_t[((y * WW + x0 + m) << 5) + c] = f2bf(vv);
    }
  }
}

// ---------------------------------------------------------------------------
// K4: conv3 32->8 (N padded to 16), NHWC bf16; pb3 staged in LDS.
// ---------------------------------------------------------------------------
__global__ __launch_bounds__(256) void conv3_mfma_kernel(
    const unsigned short* __restrict__ in_t,  // [128][256][32]
    const unsigned short* __restrict__ pb,    // [9][4][16][8]
    const float* __restrict__ bias, const float* __restrict__ gam,
    const float* __restrict__ bet, const float* __restrict__ mean,
    const float* __restrict__ var, unsigned short* __restrict__ out_t) {
  __shared__ unsigned short a_sh[3 * 66 * 32];  // 12672 B
  __shared__ unsigned short b_sh[4608];         // 9216 B (all of pb3)
  char* const ab = (char*)a_sh;
  const int bid = blockIdx.x;
  const int tid = threadIdx.x;
  MAP_YX4();
  const int lane = tid & 63;
  const int wv = tid >> 6;
  const int m0 = wv * 16;
  const int col = lane & 15;
  const int kg = lane >> 4;

  f32x4 acc = 0.f;

  {
    const bf16x8* pbv = (const bf16x8*)pb;
    bf16x8* bsl = (bf16x8*)b_sh;
    for (int s = tid; s < 576; s += 256) bsl[s] = pbv[s];
  }
  for (int i = tid; i < 792; i += 256) {  // 3*66*4
    const int r = i >> 2;
    const int q = i & 3;
    const int rowy = r / 66;
    const int xx = r % 66;
    const int gy = y + rowy - 1;
    const int gx = x0 - 1 + xx;
    bf16x8 v = {0, 0, 0, 0, 0, 0, 0, 0};
    if (gy >= 0 && gy < HH && gx >= 0 && gx < WW)
      v = *reinterpret_cast<const bf16x8*>(&in_t[((gy * WW + gx) << 5) + q * 8]);
    const int byte = ((r << 6) + (q << 4)) ^ ((r & 3) << 4);
    *reinterpret_cast<bf16x8*>(ab + byte) = v;
  }
  __syncthreads();

  const bf16x8* bsl = (const bf16x8*)b_sh;
#pragma unroll
  for (int pos = 0; pos < 9; ++pos) {
    const int ky = pos / 3;
    const int kx = pos % 3;
    const bf16x8 bv = bsl[(pos * 4 + kg) * 16 + col];
    const int r = ky * 66 + m0 + col + kx;
    const int byte = ((r << 6) + (kg << 4)) ^ ((r & 3) << 4);
    const bf16x8 av = *reinterpret_cast<const bf16x8*>(ab + byte);
    acc = __builtin_amdgcn_mfma_f32_16x16x32_bf16(av, bv, acc, 0, 0, 0);
  }

  if (col < 8) {
    const int c = col;
    const float inv = rsqrtf(var[c] + 1e-5f);
    const float sc = gam[c] * inv;
    const float sh = bet[c] - mean[c] * sc;
    const float bb = bias[c];
#pragma unroll
    for (int rr = 0; rr < 4; ++rr) {
      const int m = m0 + kg * 4 + rr;
      float vv = (acc[rr] + bb) * sc + sh;
      vv = fmaxf(vv, 0.f);
      out_t[((y * WW + x0 + m) << 3) + c] = f2bf(vv);
    }
  }
}

// ---------------------------------------------------------------------------
// K5: conv4 8->1, per-pixel direct; 128 blocks, one y-row each (XCD-mapped).
// ---------------------------------------------------------------------------
__global__ __launch_bounds__(256) void conv4_kernel(
    const unsigned short* __restrict__ in_t, const float* __restrict__ w4,
    const float* __restrict__ b4, float* __restrict__ out) {
  const int bid = blockIdx.x;
  const int y = ((bid & 7) << 4) + (bid >> 3);  // XCD k owns y in [16k,16k+16)
  const int x = threadIdx.x;

  float wr[3][3][8];
#pragma unroll
  for (int ci = 0; ci < 8; ++ci)
#pragma unroll
    for (int ky = 0; ky < 3; ++ky)
#pragma unroll
      for (int kx = 0; kx < 3; ++kx) wr[ky][kx][ci] = w4[(ci * 3 + ky) * 3 + kx];

  float acc = b4[0];
#pragma unroll
  for (int ky = 0; ky < 3; ++ky) {
    const int gy = y + ky - 1;
    if (gy < 0 || gy >= HH) continue;
#pragma unroll
    for (int kx = 0; kx < 3; ++kx) {
      const int gx = x + kx - 1;
      if (gx < 0 || gx >= WW) continue;
      const bf16x8 v =
          *reinterpret_cast<const bf16x8*>(&in_t[((gy << 8) + gx) << 3]);
#pragma unroll
      for (int ci = 0; ci < 8; ++ci) acc += bf2f(v[ci]) * wr[ky][kx][ci];
    }
  }
  out[y * WW + x] = acc;
}

// ---------------------------------------------------------------------------
extern "C" void kernel_launch(void* const* d_in, const int* in_sizes, int n_in,
                              void* d_out, int out_size, void* d_ws,
                              size_t ws_size, hipStream_t stream) {
  const float* left = (const float*)d_in[0];
  const float* right = (const float*)d_in[1];
  const float* w1 = (const float*)d_in[2];
  const float* b1 = (const float*)d_in[3];
  const float* g1 = (const float*)d_in[4];
  const float* be1 = (const float*)d_in[5];
  const float* m1 = (const float*)d_in[6];
  const float* v1 = (const float*)d_in[7];
  const float* w2 = (const float*)d_in[8];
  const float* b2 = (const float*)d_in[9];
  const float* g2 = (const float*)d_in[10];
  const float* be2 = (const float*)d_in[11];
  const float* m2 = (const float*)d_in[12];
  const float* v2 = (const float*)d_in[13];
  const float* w3 = (const float*)d_in[14];
  const float* b3 = (const float*)d_in[15];
  const float* g3 = (const float*)d_in[16];
  const float* be3 = (const float*)d_in[17];
  const float* m3 = (const float*)d_in[18];
  const float* v3 = (const float*)d_in[19];
  const float* w4 = (const float*)d_in[20];
  const float* b4 = (const float*)d_in[21];

  // Workspace:
  //  [0, 14680064)   cost_t bf16 [128][256][224]
  //  region: +0 pw1 (262144) | +262144 pb2 (65536) | +327680 pb3 (65536)
  //          +393216  o1_t bf16 [128][256][64] (4194304)
  //          +4587520 o2_t bf16 [128][256][32] (2097152)
  //          +6684672 o3_t bf16 [128][256][8]  (524288)
  char* ws = (char*)d_ws;
  unsigned short* cost_t = (unsigned short*)ws;
  char* region = ws + 14680064;
  unsigned short* pw1 = (unsigned short*)(region + 0);
  unsigned short* pb2 = (unsigned short*)(region + 262144);
  unsigned short* pb3 = (unsigned short*)(region + 327680);
  unsigned short* o1t = (unsigned short*)(region + 393216);
  unsigned short* o2t = (unsigned short*)(region + 4587520);
  unsigned short* o3t = (unsigned short*)(region + 6684672);
  float* o4 = (float*)d_out;

  k1_cv_pack<<<1106, 256, 0, stream>>>(left, right, w1, w2, w3, pw1, pb2, pb3,
                                       cost_t);
  conv1_mfma_kernel<<<256, 256, 0, stream>>>(cost_t, pw1, b1, g1, be1, m1, v1,
                                             o1t);
  conv2_mfma_kernel<<<512, 256, 0, stream>>>(o1t, pb2, b2, g2, be2, m2, v2,
                                             o2t);
  conv3_mfma_kernel<<<512, 256, 0, stream>>>(o2t, pb3, b3, g3, be3, m3, v3,
                                             o3t);
  conv4_kernel<<<128, 256, 0, stream>>>(o3t, w4, b4, o4);
}

// Round 12
// 48.240 us; speedup vs baseline: 1.0423x; 1.0423x over previous
//
#include <hip/hip_runtime.h>

#define HH 128
#define WW 256
#define CV_C 32
#define DISP 200

typedef __attribute__((ext_vector_type(4))) float f32x4;
typedef __attribute__((ext_vector_type(8))) short bf16x8;

__device__ inline unsigned short f2bf(float f) {
  unsigned int u = __float_as_uint(f);
  u = (u + 0x7FFFu + ((u >> 16) & 1u)) >> 16;  // RNE
  return (unsigned short)u;
}

__device__ inline float bf2f(short s) {
  return __uint_as_float(((unsigned int)(unsigned short)s) << 16);
}

// XCD-consistent job mapping for 512-block kernels (4 x-tiles x 128 y):
// XCD k = bid&7 owns y in [k*16, k*16+16) across ALL kernels, so each row's
// producer and consumer (and y-halo neighbors) share one XCD's L2.
#define MAP_YX4()                                   \
  const int slot = bid >> 3;                        \
  const int y = ((bid & 7) << 4) + (slot & 15);     \
  const int x0 = (slot >> 4) << 6;

// ---------------------------------------------------------------------------
// K1: blocks 0..511 cost-volume MFMA, 512..1105 weight packs (round-10 body).
// ---------------------------------------------------------------------------
__global__ __launch_bounds__(256) void k1_cv_pack(
    const float* __restrict__ left, const float* __restrict__ right,
    const float* __restrict__ w1, const float* __restrict__ w2,
    const float* __restrict__ w3, unsigned short* __restrict__ pw1,
    unsigned short* __restrict__ pb2, unsigned short* __restrict__ pb3,
    unsigned short* __restrict__ cost_t) {
  __shared__ unsigned short r_sh[272][40];  // 21760 B
  __shared__ unsigned short l_hi[64][40];   // 5120 B
  __shared__ unsigned short l_lo[64][40];   // 5120 B
  __shared__ unsigned short c_sh[64][224];  // 28672 B
  const int bid = blockIdx.x;
  const int tid = threadIdx.x;

  if (bid >= 512) {  // ---- weight packing ----
    const int b = bid - 512;
    if (b < 504) {  // pw1[chunk 7][pos 9][kg 4][n 64][j 8]
      const int idx = b * 256 + tid;
      const int j = idx & 7;
      const int n = (idx >> 3) & 63;
      const int kg = (idx >> 9) & 3;
      const int cp = idx >> 11;
      const int pos = cp % 9;
      const int chunk = cp / 9;
      const int ci = chunk * 32 + kg * 8 + j;
      float v = 0.f;
      if (ci < 200) v = w1[(n * 200 + ci) * 9 + pos];
      pw1[idx] = f2bf(v);
    } else if (b < 576) {  // pb2[pos 9][kc 2][kg 4][n 32][j 8]
      const int idx = (b - 504) * 256 + tid;
      const int j = idx & 7;
      const int n = (idx >> 3) & 31;
      const int kg = (idx >> 8) & 3;
      const int kc = (idx >> 10) & 1;
      const int pos = idx >> 11;
      const int ci = kc * 32 + kg * 8 + j;
      pb2[idx] = f2bf(w2[(n * 64 + ci) * 9 + pos]);
    } else {  // pb3[pos 9][kg 4][n 16(8 real)][j 8]
      const int idx = (b - 576) * 256 + tid;
      const int j = idx & 7;
      const int n = (idx >> 3) & 15;
      const int kg = (idx >> 7) & 3;
      const int pos = idx >> 9;
      const int ci = kg * 8 + j;
      float v = 0.f;
      if (n < 8) v = w3[(n * 32 + ci) * 9 + pos];
      pb3[idx] = f2bf(v);
    }
    return;
  }

  // ---- cost volume (proven body) ----
  MAP_YX4();
  const int lane = tid & 63;
  const int wv = tid >> 6;
  const int col = lane & 15;
  const int kg = lane >> 4;

  for (int c = wv; c < CV_C; c += 4) {
    const float v = left[(c * HH + y) * WW + x0 + lane];
    const unsigned short h = f2bf(v);
    l_hi[lane][c] = h;
    l_lo[lane][c] = f2bf(v - bf2f(h));
  }
  for (int c = wv; c < CV_C; c += 4) {
    for (int pq = 0; pq < 320; pq += 64) {
      const int p = pq + lane;
      if (p < 272) {
        const int xp = x0 - 208 + p;
        float v = (xp >= 0) ? right[(c * HH + y) * WW + xp] : 0.f;
        r_sh[p][c] = f2bf(v);
      }
    }
  }
  {
    bf16x8 z = {0, 0, 0, 0, 0, 0, 0, 0};
    bf16x8* cz = (bf16x8*)c_sh;
#pragma unroll
    for (int k = 0; k < 7; ++k) cz[k * 256 + tid] = z;
  }
  __syncthreads();

  const bf16x8 b_hi = *(const bf16x8*)&l_hi[16 * wv + col][kg * 8];
  const bf16x8 b_lo = *(const bf16x8*)&l_lo[16 * wv + col][kg * 8];

  for (int t = 0; t < 14; ++t) {
    const int pq = 16 * (wv - t) + 208;
    const bf16x8 a_r = *(const bf16x8*)&r_sh[pq + col][kg * 8];
    f32x4 acc = {0.f, 0.f, 0.f, 0.f};
    acc = __builtin_amdgcn_mfma_f32_16x16x32_bf16(a_r, b_hi, acc, 0, 0, 0);
    acc = __builtin_amdgcn_mfma_f32_16x16x32_bf16(a_r, b_lo, acc, 0, 0, 0);
#pragma unroll
    for (int r = 0; r < 4; ++r) {
      const int d = 200 - 16 * t + kg * 4 + r - col;
      if (d >= 0 && d < DISP) c_sh[16 * wv + col][d] = f2bf(acc[r]);
    }
  }
  __syncthreads();

#pragma unroll
  for (int k = 0; k < 7; ++k) {
    const int s = k * 256 + tid;
    const int x = s / 28;
    const int dv = s - x * 28;
    *reinterpret_cast<bf16x8*>(&cost_t[(y * WW + x0 + x) * 224 + dv * 8]) =
        *reinterpret_cast<const bf16x8*>(&c_sh[x][dv * 8]);
  }
}

// ---------------------------------------------------------------------------
// K2: conv1 implicit GEMM bf16 MFMA, register-blocked 4M x 2N per wave
// (round-10 body, unchanged).
// ---------------------------------------------------------------------------
__global__ __launch_bounds__(256) void conv1_mfma_kernel(
    const unsigned short* __restrict__ cost_t,  // [128][256][224]
    const unsigned short* __restrict__ pw,      // [7][9][4][64][8]
    const float* __restrict__ bias, const float* __restrict__ gam,
    const float* __restrict__ bet, const float* __restrict__ mean,
    const float* __restrict__ var, unsigned short* __restrict__ out_t) {
  __shared__ unsigned short a_sh[4 * 66 * 40];     // 21120 B
  __shared__ unsigned short b_sh[9 * 4 * 64 * 8];  // 36864 B (one chunk of pw)
  const int bid = blockIdx.x;
  const int tid = threadIdx.x;
  // XCD-consistent: XCD k = bid&7 owns y-pairs p in [8k, 8k+8).
  const int slot = bid >> 3;                       // [0,32)
  const int p = ((bid & 7) << 3) + (slot & 7);     // y-pair [0,64)
  const int y0 = p << 1;
  const int x0 = (slot >> 3) << 6;                 // [0,4)*64
  const int lane = tid & 63;
  const int wv = tid >> 6;
  const int r = wv >> 1;          // output row within pair
  const int n0 = (wv & 1) * 32;   // co half
  const int col = lane & 15;
  const int kg = lane >> 4;

  // staging slots: 4 rows x 66 x 4 q = 1056 vec8 slots, 5 iters/thread
  long goff[5];
  int laddr[5];
  bool gvalid[5], lvalid[5];
#pragma unroll
  for (int it = 0; it < 5; ++it) {
    const int i = tid + it * 256;
    lvalid[it] = i < 1056;
    const int row = i / 264;
    const int rem = i % 264;
    const int xx = rem >> 2;
    const int q = rem & 3;
    const int gy = y0 + row - 1;
    const int gx = x0 - 1 + xx;
    gvalid[it] = lvalid[it] && gy >= 0 && gy < HH && gx >= 0 && gx < WW;
    goff[it] = gvalid[it] ? (long)(gy * WW + gx) * 224 + q * 8 : 0;
    laddr[it] = (row * 66 + xx) * 40 + q * 8;
  }

  f32x4 acc[4][2];
#pragma unroll
  for (int i = 0; i < 4; ++i)
#pragma unroll
    for (int jx = 0; jx < 2; ++jx) acc[i][jx] = 0.f;

  const bf16x8* pwv = (const bf16x8*)pw;  // 2304 vec8 slots per chunk
  bf16x8* bsl = (bf16x8*)b_sh;
  const bf16x8 zero = {0, 0, 0, 0, 0, 0, 0, 0};
  bf16x8 stgA[5], stgB[9];

  // prologue: stage chunk 0 (A + B)
#pragma unroll
  for (int it = 0; it < 5; ++it)
    stgA[it] = gvalid[it] ? *reinterpret_cast<const bf16x8*>(&cost_t[goff[it]])
                          : zero;
#pragma unroll
  for (int it = 0; it < 9; ++it) stgB[it] = pwv[tid + it * 256];
#pragma unroll
  for (int it = 0; it < 5; ++it)
    if (lvalid[it]) *reinterpret_cast<bf16x8*>(&a_sh[laddr[it]]) = stgA[it];
#pragma unroll
  for (int it = 0; it < 9; ++it) bsl[tid + it * 256] = stgB[it];
  __syncthreads();

  for (int chunk = 0; chunk < 7; ++chunk) {
    if (chunk < 6) {  // prefetch next chunk into regs (hidden by MFMAs)
#pragma unroll
      for (int it = 0; it < 5; ++it)
        stgA[it] = gvalid[it] ? *reinterpret_cast<const bf16x8*>(
                                    &cost_t[goff[it] + (chunk + 1) * 32])
                              : zero;
      const bf16x8* pwn = pwv + (chunk + 1) * 2304;
#pragma unroll
      for (int it = 0; it < 9; ++it) stgB[it] = pwn[tid + it * 256];
    }
    const bf16x8* av = (const bf16x8*)a_sh;
#pragma unroll
    for (int pos = 0; pos < 9; ++pos) {
      const int ky = pos / 3;
      const int kx = pos % 3;
      const bf16x8 b0v = bsl[(pos * 4 + kg) * 64 + n0 + col];
      const bf16x8 b1v = bsl[(pos * 4 + kg) * 64 + n0 + 16 + col];
      bf16x8 af[4];
#pragma unroll
      for (int mt = 0; mt < 4; ++mt)
        af[mt] = av[((r + ky) * 66 + mt * 16 + col + kx) * 5 + kg];
#pragma unroll
      for (int mt = 0; mt < 4; ++mt) {
        acc[mt][0] =
            __builtin_amdgcn_mfma_f32_16x16x32_bf16(af[mt], b0v, acc[mt][0], 0, 0, 0);
        acc[mt][1] =
            __builtin_amdgcn_mfma_f32_16x16x32_bf16(af[mt], b1v, acc[mt][1], 0, 0, 0);
      }
    }
    if (chunk < 6) {
      __syncthreads();  // all waves done reading a_sh/b_sh for this chunk
#pragma unroll
      for (int it = 0; it < 5; ++it)
        if (lvalid[it]) *reinterpret_cast<bf16x8*>(&a_sh[laddr[it]]) = stgA[it];
#pragma unroll
      for (int it = 0; it < 9; ++it) bsl[tid + it * 256] = stgB[it];
      __syncthreads();  // new chunk visible
    }
  }

  // epilogue: bias + BN + ReLU -> o1_t NHWC bf16 [128][256][64]
  const int y = y0 + r;
#pragma unroll
  for (int nf = 0; nf < 2; ++nf) {
    const int c = n0 + nf * 16 + col;
    const float inv = rsqrtf(var[c] + 1e-5f);
    const float sc = gam[c] * inv;
    const float sh = bet[c] - mean[c] * sc;
    const float bb = bias[c];
#pragma unroll
    for (int mt = 0; mt < 4; ++mt) {
#pragma unroll
      for (int rr = 0; rr < 4; ++rr) {
        const int m = mt * 16 + kg * 4 + rr;
        float vv = (acc[mt][nf][rr] + bb) * sc + sh;
        vv = fmaxf(vv, 0.f);
        out_t[((y * WW + x0 + m) << 6) + c] = f2bf(vv);
      }
    }
  }
}

// ---------------------------------------------------------------------------
// K3: conv2 64->32, NHWC bf16, XOR-swizzled A-tile; full pb2 staged in LDS
// (round-10 body, unchanged).
// ---------------------------------------------------------------------------
__global__ __launch_bounds__(256) void conv2_mfma_kernel(
    const unsigned short* __restrict__ in_t,  // [128][256][64]
    const unsigned short* __restrict__ pb,    // [9][2][4][32][8]
    const float* __restrict__ bias, const float* __restrict__ gam,
    const float* __restrict__ bet, const float* __restrict__ mean,
    const float* __restrict__ var, unsigned short* __restrict__ out_t) {
  __shared__ unsigned short a_sh[3 * 66 * 64];  // 25344 B
  __shared__ unsigned short b_sh[18432];        // 36864 B (all of pb2)
  char* const ab = (char*)a_sh;
  const int bid = blockIdx.x;
  const int tid = threadIdx.x;
  MAP_YX4();
  const int lane = tid & 63;
  const int wv = tid >> 6;
  const int m0 = (wv >> 1) * 32;
  const int n0 = (wv & 1) * 16;
  const int col = lane & 15;
  const int kg = lane >> 4;

  f32x4 acc[2];
  acc[0] = 0.f;
  acc[1] = 0.f;

  {  // stage all weights (2304 vec8 = 9/thread)
    const bf16x8* pbv = (const bf16x8*)pb;
    bf16x8* bsl = (bf16x8*)b_sh;
#pragma unroll
    for (int it = 0; it < 9; ++it) bsl[tid + it * 256] = pbv[tid + it * 256];
  }
  for (int i = tid; i < 1584; i += 256) {  // 3*66*8
    const int r = i >> 3;
    const int q = i & 7;
    const int rowy = r / 66;
    const int xx = r % 66;
    const int gy = y + rowy - 1;
    const int gx = x0 - 1 + xx;
    bf16x8 v = {0, 0, 0, 0, 0, 0, 0, 0};
    if (gy >= 0 && gy < HH && gx >= 0 && gx < WW)
      v = *reinterpret_cast<const bf16x8*>(&in_t[((gy * WW + gx) << 6) + q * 8]);
    const int byte = ((r << 7) + (q << 4)) ^ ((r & 7) << 4);
    *reinterpret_cast<bf16x8*>(ab + byte) = v;
  }
  __syncthreads();

  const bf16x8* bsl = (const bf16x8*)b_sh;
#pragma unroll
  for (int pos = 0; pos < 9; ++pos) {
    const int ky = pos / 3;
    const int kx = pos % 3;
#pragma unroll
    for (int kc = 0; kc < 2; ++kc) {
      const bf16x8 bv = bsl[((pos * 2 + kc) * 4 + kg) * 32 + n0 + col];
#pragma unroll
      for (int mf = 0; mf < 2; ++mf) {
        const int r = ky * 66 + m0 + mf * 16 + col + kx;
        const int byte = ((r << 7) + (kc << 6) + (kg << 4)) ^ ((r & 7) << 4);
        const bf16x8 av = *reinterpret_cast<const bf16x8*>(ab + byte);
        acc[mf] = __builtin_amdgcn_mfma_f32_16x16x32_bf16(av, bv, acc[mf], 0, 0, 0);
      }
    }
  }

  const int c = n0 + col;
  const float inv = rsqrtf(var[c] + 1e-5f);
  const float sc = gam[c] * inv;
  const float sh = bet[c] - mean[c] * sc;
  const float bb = bias[c];
#pragma unroll
  for (int mf = 0; mf < 2; ++mf) {
#pragma unroll
    for (int rr = 0; rr < 4; ++rr) {
      const int m = m0 + mf * 16 + kg * 4 + rr;
      float vv = (acc[mf][rr] + bb) * sc + sh;
      vv = fmaxf(vv, 0.f);
      out_t[((y * WW + x0 + m) << 5) + c] = f2bf(vv);
    }
  }
}

// ---------------------------------------------------------------------------
// K4: FUSED conv3 (32->8, MFMA, y-halo recompute x3 rows) + conv4 (8->1).
// Block: final-output row y, 64 px. Stages o2t rows y-2..y+2 x 84 cols,
// computes conv3 for rows y-1..y+1 x 80 px into an LDS o3 tile (zero outside
// image => conv4's SAME padding), then conv4 reads the tile. conv3 per-output
// math/order identical to the previous separate kernel -> bit-identical.
// ---------------------------------------------------------------------------
__global__ __launch_bounds__(256) void conv34_fused_kernel(
    const unsigned short* __restrict__ in_t,  // o2t [128][256][32]
    const unsigned short* __restrict__ pb,    // pb3 [9][4][16][8]
    const float* __restrict__ bias, const float* __restrict__ gam,
    const float* __restrict__ bet, const float* __restrict__ mean,
    const float* __restrict__ var, const float* __restrict__ w4,
    const float* __restrict__ b4, float* __restrict__ out) {
  __shared__ unsigned short o2s[5 * 84 * 32];  // 26880 B, swizzled
  __shared__ unsigned short b_sh[4608];        // 9216 B (all of pb3)
  __shared__ unsigned short o3s[3 * 80 * 8];   // 3840 B
  char* const ab = (char*)o2s;
  const int bid = blockIdx.x;
  const int tid = threadIdx.x;
  MAP_YX4();
  const int lane = tid & 63;
  const int wv = tid >> 6;
  const int col = lane & 15;
  const int kg = lane >> 4;

  {  // stage pb3
    const bf16x8* pbv = (const bf16x8*)pb;
    bf16x8* bsl = (bf16x8*)b_sh;
    for (int s = tid; s < 576; s += 256) bsl[s] = pbv[s];
  }
  if (tid < 240) {  // zero o3 tile (out-of-image rows/px stay zero)
    bf16x8 z = {0, 0, 0, 0, 0, 0, 0, 0};
    ((bf16x8*)o3s)[tid] = z;
  }
  // stage o2t rows y-2..y+2, cols x0-2..x0+81 (swizzled, zero outside image)
  for (int i = tid; i < 1680; i += 256) {  // 5*84*4
    const int r = i >> 2;
    const int q = i & 3;
    const int rowy = r / 84;
    const int xx = r % 84;
    const int gy = y - 2 + rowy;
    const int gx = x0 - 2 + xx;
    bf16x8 v = {0, 0, 0, 0, 0, 0, 0, 0};
    if (gy >= 0 && gy < HH && gx >= 0 && gx < WW)
      v = *reinterpret_cast<const bf16x8*>(&in_t[((gy * WW + gx) << 5) + q * 8]);
    const int byte = ((r << 6) + (q << 4)) ^ ((r & 3) << 4);
    *reinterpret_cast<bf16x8*>(ab + byte) = v;
  }
  __syncthreads();

  // conv3: 15 jobs = 3 output rows (y-1..y+1) x 5 x-tiles (px x0-1..x0+78)
  const bf16x8* bsl = (const bf16x8*)b_sh;
  const int c3 = col < 8 ? col : 7;
  const float inv3 = rsqrtf(var[c3] + 1e-5f);
  const float sc3 = gam[c3] * inv3;
  const float sh3 = bet[c3] - mean[c3] * sc3;
  const float bb3 = bias[c3];

  for (int jb = wv; jb < 15; jb += 4) {
    const int ry = jb / 5;   // 0..2 -> output row y-1+ry
    const int xt = jb % 5;   // x-tile; local px = 16*xt + m
    f32x4 acc = {0.f, 0.f, 0.f, 0.f};
#pragma unroll
    for (int pos = 0; pos < 9; ++pos) {
      const int ky = pos / 3;
      const int kx = pos % 3;
      const bf16x8 bv = bsl[(pos * 4 + kg) * 16 + col];
      const int r = (ry + ky) * 84 + 16 * xt + col + kx;
      const int byte = ((r << 6) + (kg << 4)) ^ ((r & 3) << 4);
      const bf16x8 av = *reinterpret_cast<const bf16x8*>(ab + byte);
      acc = __builtin_amdgcn_mfma_f32_16x16x32_bf16(av, bv, acc, 0, 0, 0);
    }
    if (col < 8) {
      const int gyo = y - 1 + ry;
#pragma unroll
      for (int rr = 0; rr < 4; ++rr) {
        const int pxl = 16 * xt + kg * 4 + rr;  // gx = x0-1+pxl
        const int gxo = x0 - 1 + pxl;
        if (gyo >= 0 && gyo < HH && gxo >= 0 && gxo < WW) {
          float vv = (acc[rr] + bb3) * sc3 + sh3;
          vv = fmaxf(vv, 0.f);
          o3s[(ry * 80 + pxl) * 8 + col] = f2bf(vv);
        }
      }
    }
  }
  __syncthreads();

  // conv4: 64 px, one per lane of wave 0
  if (tid < 64) {
    const int x = x0 + tid;
    float wr[3][3][8];
#pragma unroll
    for (int ci = 0; ci < 8; ++ci)
#pragma unroll
      for (int ky = 0; ky < 3; ++ky)
#pragma unroll
        for (int kx = 0; kx < 3; ++kx)
          wr[ky][kx][ci] = w4[(ci * 3 + ky) * 3 + kx];
    float acc = b4[0];
    const bf16x8* o3v = (const bf16x8*)o3s;
#pragma unroll
    for (int ky = 0; ky < 3; ++ky) {
#pragma unroll
      for (int kx = 0; kx < 3; ++kx) {
        const bf16x8 v = o3v[ky * 80 + tid + kx];
#pragma unroll
        for (int ci = 0; ci < 8; ++ci) acc += bf2f(v[ci]) * wr[ky][kx][ci];
      }
    }
    out[y * WW + x] = acc;
  }
}

// ---------------------------------------------------------------------------
extern "C" void kernel_launch(void* const* d_in, const int* in_sizes, int n_in,
                              void* d_out, int out_size, void* d_ws,
                              size_t ws_size, hipStream_t stream) {
  const float* left = (const float*)d_in[0];
  const float* right = (const float*)d_in[1];
  const float* w1 = (const float*)d_in[2];
  const float* b1 = (const float*)d_in[3];
  const float* g1 = (const float*)d_in[4];
  const float* be1 = (const float*)d_in[5];
  const float* m1 = (const float*)d_in[6];
  const float* v1 = (const float*)d_in[7];
  const float* w2 = (const float*)d_in[8];
  const float* b2 = (const float*)d_in[9];
  const float* g2 = (const float*)d_in[10];
  const float* be2 = (const float*)d_in[11];
  const float* m2 = (const float*)d_in[12];
  const float* v2 = (const float*)d_in[13];
  const float* w3 = (const float*)d_in[14];
  const float* b3 = (const float*)d_in[15];
  const float* g3 = (const float*)d_in[16];
  const float* be3 = (const float*)d_in[17];
  const float* m3 = (const float*)d_in[18];
  const float* v3 = (const float*)d_in[19];
  const float* w4 = (const float*)d_in[20];
  const float* b4 = (const float*)d_in[21];

  // Workspace:
  //  [0, 14680064)   cost_t bf16 [128][256][224]
  //  region: +0 pw1 (262144) | +262144 pb2 (65536) | +327680 pb3 (65536)
  //          +393216  o1_t bf16 [128][256][64] (4194304)
  //          +4587520 o2_t bf16 [128][256][32] (2097152)
  char* ws = (char*)d_ws;
  unsigned short* cost_t = (unsigned short*)ws;
  char* region = ws + 14680064;
  unsigned short* pw1 = (unsigned short*)(region + 0);
  unsigned short* pb2 = (unsigned short*)(region + 262144);
  unsigned short* pb3 = (unsigned short*)(region + 327680);
  unsigned short* o1t = (unsigned short*)(region + 393216);
  unsigned short* o2t = (unsigned short*)(region + 4587520);
  float* o4 = (float*)d_out;

  k1_cv_pack<<<1106, 256, 0, stream>>>(left, right, w1, w2, w3, pw1, pb2, pb3,
                                       cost_t);
  conv1_mfma_kernel<<<256, 256, 0, stream>>>(cost_t, pw1, b1, g1, be1, m1, v1,
                                             o1t);
  conv2_mfma_kernel<<<512, 256, 0, stream>>>(o1t, pb2, b2, g2, be2, m2, v2,
                                             o2t);
  conv34_fused_kernel<<<512, 256, 0, stream>>>(o2t, pb3, b3, g3, be3, m3, v3,
                                               w4, b4, o4);
}